// Round 1
// baseline (517.878 us; speedup 1.0000x reference)
//
#include <hip/hip_runtime.h>
#include <math.h>

#define B_  32
#define T_  4096
#define H_  256
#define D_  512

// ws layout (bytes):
//   pre    : float [32*256]    @ 0        (h_proj + b_attn)
//   we_hi  : ushort[256*512]   @ 32768
//   we_lo  : ushort[256*512]   @ 294912
//   scores : float [32*4096]   @ 557056
// total 1081344 bytes
#define WS_PRE    0
#define WS_WEHI   32768
#define WS_WELO   294912
#define WS_SCORES 557056

using short8  = __attribute__((ext_vector_type(8))) short;
using float4v = __attribute__((ext_vector_type(4))) float;

__device__ __forceinline__ unsigned short f32_to_bf16_rne(float x) {
    unsigned u = __float_as_uint(x);
    unsigned r = u + 0x7fffu + ((u >> 16) & 1u);
    return (unsigned short)(r >> 16);
}
__device__ __forceinline__ float bf16_to_f32(unsigned short h) {
    return __uint_as_float(((unsigned)h) << 16);
}

// ---------------------------------------------------------------- prep ------
// blocks 0..31 : pre[b][h] = b_attn[h] + hidden[b] . W_attn[h, 0:512]
// blocks 32..39: W_e = W_attn[:, 512:1024] -> bf16 hi/lo into ws
// block  40    : zero the context region of d_out
__global__ __launch_bounds__(256)
void prep_kernel(const float* __restrict__ hidden,
                 const float* __restrict__ W_attn,
                 const float* __restrict__ b_attn,
                 unsigned char* __restrict__ ws,
                 float* __restrict__ out_ctx) {
    int blk = blockIdx.x;
    int tid = threadIdx.x;
    if (blk < 32) {
        int b = blk, h = tid;
        const float4* hv = (const float4*)(hidden + b * D_);
        const float4* wv = (const float4*)(W_attn + (size_t)h * 1024);
        float s = 0.f;
        #pragma unroll 4
        for (int d4 = 0; d4 < D_ / 4; ++d4) {
            float4 a = hv[d4], w = wv[d4];
            s += a.x * w.x + a.y * w.y + a.z * w.z + a.w * w.w;
        }
        ((float*)(ws + WS_PRE))[b * H_ + h] = s + b_attn[h];
    } else if (blk < 40) {
        int base = (blk - 32) * 16384 + tid;
        unsigned short* whi = (unsigned short*)(ws + WS_WEHI);
        unsigned short* wlo = (unsigned short*)(ws + WS_WELO);
        #pragma unroll 4
        for (int i = 0; i < 64; ++i) {
            int idx = base + i * 256;          // 0..131071
            int n = idx >> 9, k = idx & 511;
            float x = W_attn[(size_t)n * 1024 + 512 + k];
            unsigned short hi = f32_to_bf16_rne(x);
            unsigned short lo = f32_to_bf16_rne(x - bf16_to_f32(hi));
            whi[idx] = hi;
            wlo[idx] = lo;
        }
    } else {
        for (int i = tid; i < B_ * D_; i += 256) out_ctx[i] = 0.f;
    }
}

// --------------------------------------------------- GEMM + tanh + v-dot ----
// grid = 1024 blocks (M-tiles of 128 rows), 512 threads (8 waves, 2x4 m x n).
// Per block: BM=128 x BN=256 (full N) x K=512, BK=32.
// Split-bf16: acc += Ah*Bh + Al*Bh + Ah*Bl  (Al*Bl dropped, rel ~2^-18).
#define BM 128
#define BN 256
#define BK 32
#define LDT 40   // LDS row stride in ushorts (32 + 8 pad -> 2-way-only bank aliasing)

__global__ __launch_bounds__(512, 2)
void gemm_scores_kernel(const float* __restrict__ enc,
                        const unsigned char* __restrict__ ws_ro,
                        const float* __restrict__ v,
                        float* __restrict__ scores_out) {
    __shared__ unsigned short sAh[BM * LDT], sAl[BM * LDT];
    __shared__ unsigned short sBh[BN * LDT], sBl[BN * LDT];
    __shared__ float sScore[BM];

    const float*          pre = (const float*)(ws_ro + WS_PRE);
    const unsigned short* weh = (const unsigned short*)(ws_ro + WS_WEHI);
    const unsigned short* wel = (const unsigned short*)(ws_ro + WS_WELO);

    int tid = threadIdx.x;
    int m0  = blockIdx.x * BM;
    int b   = m0 >> 12;            // 4096 rows per batch, tiles never straddle b

    if (tid < BM) sScore[tid] = 0.f;

    // A staging: thread -> (row, 8-float column group)
    int rowA = tid >> 2, cgA = tid & 3;
    const float* gA = enc + (size_t)(m0 + rowA) * D_ + cgA * 8;
    // B staging: thread -> (n-row, 16-ushort half)
    int rowB = tid >> 1, hB = tid & 1;
    const unsigned short* gBh = weh + (size_t)rowB * D_ + hB * 16;
    const unsigned short* gBl = wel + (size_t)rowB * D_ + hB * 16;

    int wave = tid >> 6, lane = tid & 63;
    int wm = wave & 1, wn = wave >> 1;   // 2 m-waves x 4 n-waves, 64x64 each
    int quad = lane >> 4, l16 = lane & 15;

    float4v acc[4][4] = {};

    // register prefetch buffers
    float a_reg[8];
    uint4 bhr0, bhr1, blr0, blr1;
    {
        const float4* p = (const float4*)gA;
        *(float4*)(a_reg)     = p[0];
        *(float4*)(a_reg + 4) = p[1];
        bhr0 = ((const uint4*)gBh)[0]; bhr1 = ((const uint4*)gBh)[1];
        blr0 = ((const uint4*)gBl)[0]; blr1 = ((const uint4*)gBl)[1];
    }

    const int KIT = D_ / BK;   // 16
    for (int kk = 0; kk < KIT; ++kk) {
        // convert + write staged regs to LDS
        unsigned short hi8[8], lo8[8];
        #pragma unroll
        for (int j = 0; j < 8; ++j) {
            float x = a_reg[j];
            unsigned short h = f32_to_bf16_rne(x);
            hi8[j] = h;
            lo8[j] = f32_to_bf16_rne(x - bf16_to_f32(h));
        }
        *(short8*)&sAh[rowA * LDT + cgA * 8] = *(short8*)hi8;
        *(short8*)&sAl[rowA * LDT + cgA * 8] = *(short8*)lo8;
        *(uint4*)&sBh[rowB * LDT + hB * 16]     = bhr0;
        *(uint4*)&sBh[rowB * LDT + hB * 16 + 8] = bhr1;
        *(uint4*)&sBl[rowB * LDT + hB * 16]     = blr0;
        *(uint4*)&sBl[rowB * LDT + hB * 16 + 8] = blr1;
        __syncthreads();

        // prefetch next K-chunk (latency hidden behind the MFMA block below)
        if (kk + 1 < KIT) {
            const float4* p = (const float4*)(gA + (kk + 1) * BK);
            *(float4*)(a_reg)     = p[0];
            *(float4*)(a_reg + 4) = p[1];
            const uint4* pbh = (const uint4*)(gBh + (kk + 1) * BK);
            const uint4* pbl = (const uint4*)(gBl + (kk + 1) * BK);
            bhr0 = pbh[0]; bhr1 = pbh[1];
            blr0 = pbl[0]; blr1 = pbl[1];
        }

        short8 ah[4], al[4], bh[4], bl[4];
        #pragma unroll
        for (int i = 0; i < 4; ++i) {
            int r = wm * 64 + i * 16 + l16;
            ah[i] = *(const short8*)&sAh[r * LDT + quad * 8];
            al[i] = *(const short8*)&sAl[r * LDT + quad * 8];
        }
        #pragma unroll
        for (int j = 0; j < 4; ++j) {
            int c = wn * 64 + j * 16 + l16;
            bh[j] = *(const short8*)&sBh[c * LDT + quad * 8];
            bl[j] = *(const short8*)&sBl[c * LDT + quad * 8];
        }
        #pragma unroll
        for (int i = 0; i < 4; ++i) {
            #pragma unroll
            for (int j = 0; j < 4; ++j) {
                acc[i][j] = __builtin_amdgcn_mfma_f32_16x16x32_bf16(ah[i], bh[j], acc[i][j], 0, 0, 0);
                acc[i][j] = __builtin_amdgcn_mfma_f32_16x16x32_bf16(al[i], bh[j], acc[i][j], 0, 0, 0);
                acc[i][j] = __builtin_amdgcn_mfma_f32_16x16x32_bf16(ah[i], bl[j], acc[i][j], 0, 0, 0);
            }
        }
        __syncthreads();
    }

    // epilogue: energy = tanh(acc + pre[b][n]); score_row += energy * v[n]
    float rowsum[4][4] = {};
    #pragma unroll
    for (int j = 0; j < 4; ++j) {
        int n = wn * 64 + j * 16 + l16;
        float pv = pre[b * H_ + n];
        float vv = v[n];
        #pragma unroll
        for (int i = 0; i < 4; ++i) {
            #pragma unroll
            for (int r = 0; r < 4; ++r) {
                float e = tanhf(acc[i][j][r] + pv);
                rowsum[i][r] += e * vv;
            }
        }
    }
    // reduce over the 16 lanes sharing a row (low 4 lane bits)
    #pragma unroll
    for (int i = 0; i < 4; ++i) {
        #pragma unroll
        for (int r = 0; r < 4; ++r) {
            float s = rowsum[i][r];
            s += __shfl_xor(s, 1);
            s += __shfl_xor(s, 2);
            s += __shfl_xor(s, 4);
            s += __shfl_xor(s, 8);
            rowsum[i][r] = s;
        }
    }
    if (l16 == 0) {
        #pragma unroll
        for (int i = 0; i < 4; ++i) {
            #pragma unroll
            for (int r = 0; r < 4; ++r) {
                int row = wm * 64 + i * 16 + quad * 4 + r;
                atomicAdd(&sScore[row], rowsum[i][r]);
            }
        }
    }
    __syncthreads();
    if (tid < BM) scores_out[m0 + tid] = sScore[tid];
}

// ------------------------------------------------------------- softmax ------
// one block per batch, 1024 threads, 4 scores each (float4)
__global__ __launch_bounds__(1024)
void softmax_kernel(const float* __restrict__ scores, float* __restrict__ wout) {
    __shared__ float red[16];
    int b = blockIdx.x, tid = threadIdx.x;
    int wave = tid >> 6, lane = tid & 63;
    float4 x = ((const float4*)(scores + (size_t)b * T_))[tid];

    float m = fmaxf(fmaxf(x.x, x.y), fmaxf(x.z, x.w));
    #pragma unroll
    for (int off = 32; off; off >>= 1) m = fmaxf(m, __shfl_xor(m, off));
    if (lane == 0) red[wave] = m;
    __syncthreads();
    if (wave == 0) {
        float t = (lane < 16) ? red[lane] : -1e30f;
        #pragma unroll
        for (int off = 8; off; off >>= 1) t = fmaxf(t, __shfl_xor(t, off));
        if (lane == 0) red[0] = t;
    }
    __syncthreads();
    m = red[0];
    __syncthreads();

    float4 e;
    e.x = expf(x.x - m); e.y = expf(x.y - m);
    e.z = expf(x.z - m); e.w = expf(x.w - m);
    float s = e.x + e.y + e.z + e.w;
    #pragma unroll
    for (int off = 32; off; off >>= 1) s += __shfl_xor(s, off);
    if (lane == 0) red[wave] = s;
    __syncthreads();
    if (wave == 0) {
        float t = (lane < 16) ? red[lane] : 0.f;
        #pragma unroll
        for (int off = 8; off; off >>= 1) t += __shfl_xor(t, off);
        if (lane == 0) red[0] = t;
    }
    __syncthreads();
    float inv = 1.0f / red[0];

    float4 o;
    o.x = e.x * inv; o.y = e.y * inv; o.z = e.z * inv; o.w = e.w * inv;
    ((float4*)(wout + (size_t)b * T_))[tid] = o;
}

// ------------------------------------------------------------- context ------
// grid = 32 b x 32 chunks (128 rows each), 256 threads.
// thread: 4 contiguous d-columns, 2 row-interleaved accumulators -> atomicAdd
__global__ __launch_bounds__(256)
void context_kernel(const float* __restrict__ enc,
                    const float* __restrict__ w,
                    float* __restrict__ ctx) {
    int blk = blockIdx.x;
    int b = blk >> 5, chunk = blk & 31;
    int tid = threadIdx.x;
    int colg = tid & 127, rh = tid >> 7;
    const float* encb = enc + (size_t)b * T_ * D_;
    int t0 = chunk * 128;

    float4 acc = {0.f, 0.f, 0.f, 0.f};
    #pragma unroll 4
    for (int s = 0; s < 64; ++s) {
        int t = t0 + rh + 2 * s;
        float wt = w[(size_t)b * T_ + t];
        float4 ev = *(const float4*)(encb + (size_t)t * D_ + colg * 4);
        acc.x += wt * ev.x; acc.y += wt * ev.y;
        acc.z += wt * ev.z; acc.w += wt * ev.w;
    }
    __shared__ float4 sred[128];
    if (rh == 1) sred[colg] = acc;
    __syncthreads();
    if (rh == 0) {
        float4 o = sred[colg];
        acc.x += o.x; acc.y += o.y; acc.z += o.z; acc.w += o.w;
        float* dst = ctx + (size_t)b * D_ + colg * 4;
        atomicAdd(dst + 0, acc.x);
        atomicAdd(dst + 1, acc.y);
        atomicAdd(dst + 2, acc.z);
        atomicAdd(dst + 3, acc.w);
    }
}

// ------------------------------------------------------------- launcher -----
extern "C" void kernel_launch(void* const* d_in, const int* in_sizes, int n_in,
                              void* d_out, int out_size, void* d_ws, size_t ws_size,
                              hipStream_t stream) {
    const float* hidden = (const float*)d_in[0];   // (32, 512)
    const float* enc    = (const float*)d_in[1];   // (32, 4096, 512)
    const float* W_attn = (const float*)d_in[2];   // (256, 1024)
    const float* b_attn = (const float*)d_in[3];   // (256,)
    const float* v      = (const float*)d_in[4];   // (256,)
    float* out = (float*)d_out;                    // context(16384) ++ weights(131072)
    unsigned char* ws = (unsigned char*)d_ws;
    float* scores = (float*)(ws + WS_SCORES);

    prep_kernel<<<41, 256, 0, stream>>>(hidden, W_attn, b_attn, ws, out);
    gemm_scores_kernel<<<T_ * B_ / BM, 512, 0, stream>>>(enc, ws, v, scores);
    softmax_kernel<<<B_, 1024, 0, stream>>>(scores, out + B_ * D_);
    context_kernel<<<B_ * 32, 256, 0, stream>>>(enc, out + B_ * D_, out);
}